// Round 11
// baseline (511.507 us; speedup 1.0000x reference)
//
#include <hip/hip_runtime.h>
#include <cstdint>
#include <cstddef>

typedef __attribute__((ext_vector_type(8))) _Float16 f16x8;
typedef __attribute__((ext_vector_type(4))) _Float16 f16x4;
typedef __attribute__((ext_vector_type(4))) float f32x4;

__device__ __forceinline__ f16x8 cvt8(const float4& p, const float4& q) {
  f16x8 r;
  r[0] = (_Float16)p.x; r[1] = (_Float16)p.y; r[2] = (_Float16)p.z; r[3] = (_Float16)p.w;
  r[4] = (_Float16)q.x; r[5] = (_Float16)q.y; r[6] = (_Float16)q.z; r[7] = (_Float16)q.w;
  return r;
}

// ---------------- merged prep (+ cnt zeroing) ----------------
// Bf (f16, gemm1): 896x64 fused weight = [Wf(768) | W1[0:64] | W1[64:80] | W1[112:144] | 0]
// CONTIGUOUS bijection (matches gemm1's LDS/A reads): chunk=gk>>5, k=gk&31, g=k>>3, j=k&7
//   Bf[((chunk*4+g)*64 + col)*8 + j]
// biasf: llm_proj_b routed through W1.  B2f (f16, gemm2): same g*8+j bijection.

__global__ void prep_kernel(const float* __restrict__ pw, const float* __restrict__ pb,
                            const float* __restrict__ w1, const float* __restrict__ w2,
                            _Float16* __restrict__ Bf, float* __restrict__ biasf,
                            _Float16* __restrict__ B2f, int* __restrict__ cnt, int n) {
  int idx = blockIdx.x * 256 + threadIdx.x;
  if (idx < n) cnt[idx] = 0;
  if (idx < 896 * 64) {
    int gk = idx >> 6, col = idx & 63;
    float val;
    if (gk < 768) {
      float acc = 0.0f;
      #pragma unroll 8
      for (int m = 0; m < 32; ++m) acc = fmaf(pw[gk * 32 + m], w1[(80 + m) * 64 + col], acc);
      val = acc;
    } else if (gk < 832) val = w1[(gk - 768) * 64 + col];
    else if (gk < 848)   val = w1[(64 + gk - 832) * 64 + col];
    else if (gk < 880)   val = w1[(112 + gk - 848) * 64 + col];
    else                 val = 0.0f;
    int chunk = gk >> 5, k = gk & 31;
    int g = k >> 3, j = k & 7;
    Bf[((size_t)(chunk * 4 + g) * 64 + col) * 8 + j] = (_Float16)val;
  } else if (idx < 896 * 64 + 64) {
    int col = idx - 896 * 64;
    float acc = 0.0f;
    for (int m = 0; m < 32; ++m) acc = fmaf(pb[m], w1[(80 + m) * 64 + col], acc);
    biasf[col] = acc;
  } else if (idx < 896 * 64 + 64 + 64 * 64) {
    int q2 = idx - (896 * 64 + 64);
    int gk = q2 >> 6, col = q2 & 63;
    float val = w2[gk * 64 + col];
    int chunk = gk >> 5, k = gk & 31;
    int g = k >> 3, j = k & 7;
    B2f[((size_t)(chunk * 4 + g) * 64 + col) * 8 + j] = (_Float16)val;
  }
}

// ---------------- CSR build (shifted colp: end(j)=colp[j], start(j)=colp[j-1]) ----------------

__global__ void cnt_kernel(const int* __restrict__ ei, int* __restrict__ cnt, int E) {
  int e = blockIdx.x * 256 + threadIdx.x;
  if (e < E) atomicAdd(&cnt[ei[E + e]], 1);
}

__global__ __launch_bounds__(256) void scan_blk(const int* __restrict__ cnt,
                                                int* __restrict__ colp,
                                                int* __restrict__ bsum, int n) {
  __shared__ int ws[4];
  int t = threadIdx.x, lane = t & 63, w = t >> 6;
  int i = blockIdx.x * 256 + t;
  int v = (i < n) ? cnt[i] : 0;
  int x = v;
  #pragma unroll
  for (int off = 1; off < 64; off <<= 1) { int y = __shfl_up(x, off); if (lane >= off) x += y; }
  if (lane == 63) ws[w] = x;
  __syncthreads();
  if (t == 0) {
    int s = 0;
    #pragma unroll
    for (int k = 0; k < 4; ++k) { int tmp = ws[k]; ws[k] = s; s += tmp; }
    bsum[blockIdx.x] = s;
  }
  __syncthreads();
  if (i < n) colp[i] = ws[w] + x - v;
}

__global__ __launch_bounds__(512) void scan_top(int* __restrict__ bsum,
                                                int* __restrict__ colp, int nb, int n) {
  __shared__ int ws[8];
  int t = threadIdx.x, lane = t & 63, w = t >> 6;
  int v = (t < nb) ? bsum[t] : 0;
  int x = v;
  #pragma unroll
  for (int off = 1; off < 64; off <<= 1) { int y = __shfl_up(x, off); if (lane >= off) x += y; }
  if (lane == 63) ws[w] = x;
  __syncthreads();
  if (t == 0) {
    int s = 0;
    #pragma unroll
    for (int k = 0; k < 8; ++k) { int tmp = ws[k]; ws[k] = s; s += tmp; }
  }
  __syncthreads();
  int excl = ws[w] + x - v;
  if (t < nb) bsum[t] = excl;
  if (t == nb - 1) colp[n] = excl + v;
}

__global__ void scan_add(int* __restrict__ colp, const int* __restrict__ bsum, int n) {
  int i = blockIdx.x * 256 + threadIdx.x;
  if (i < n) colp[i] += bsum[blockIdx.x];
}

__global__ void fill_kernel(const int* __restrict__ ei, const float* __restrict__ ew,
                            int* __restrict__ colp, int2* __restrict__ csr, int E) {
  int e = blockIdx.x * 256 + threadIdx.x;
  if (e >= E) return;
  int row = ei[e], col = ei[E + e];
  int pos = atomicAdd(&colp[col], 1);
  csr[pos] = make_int2(row, __float_as_int(ew[e]));
}

__global__ void degsum_kernel(const int* __restrict__ colp, const int2* __restrict__ csr,
                              float* __restrict__ dinv, int n) {
  int j = blockIdx.x * 256 + threadIdx.x;
  if (j >= n) return;
  int e0 = (j > 0) ? colp[j - 1] : 0;
  int e1 = colp[j];
  float s = 1.0f;
  for (int e = e0; e < e1; ++e) s += __int_as_float(csr[e].y);
  dinv[j] = rsqrtf(s);
}

// ---------------- gemm1: LINEAR-staged LDS MFMA ----------------
// Block owns 32 consecutive rows (96 KB contiguous llm). Stage: fully linear
// f32 reads -> f16 LDS (48.5 KB -> 3 blocks/CU; staging blocks overlap computing
// blocks). Compute: wave wv = rows (wv&1)*16, cols (wv>>1)*32.
// epilogue: hp(f16) = dinv*(x@W1 + biasf)

#define G1_ROWS 32
#define G1_STR  776   // f16 per LDS row (768 + 8 pad): 1552 B, 16B-aligned rows

__global__ __launch_bounds__(256, 3) void gemm1_kernel(
    const float* __restrict__ llm, const _Float16* __restrict__ Bf,
    const int* __restrict__ names, const int* __restrict__ types,
    const float* __restrict__ beh, const float* __restrict__ nemb,
    const float* __restrict__ temb, const float* __restrict__ biasf,
    const float* __restrict__ dinv, _Float16* __restrict__ out, int n)
{
  __shared__ _Float16 As[G1_ROWS][G1_STR];

  // bijective XCD swizzle
  int nwg = gridDim.x;
  int b = blockIdx.x;
  int q = nwg >> 3, r = nwg & 7;
  int xcd = b & 7, bidx = b >> 3;
  int swz = (xcd < r ? xcd * (q + 1) : r * (q + 1) + (xcd - r) * q) + bidx;

  const int tid = threadIdx.x;
  const int base = swz * G1_ROWS;

  // ---- stage: 32 rows x 768 f32, read LINEARLY, store f16 ----
  const float* srcbase = llm + (size_t)base * 768;
  bool safe = (base + G1_ROWS <= n);
  #pragma unroll
  for (int i = 0; i < 24; ++i) {
    int f = i * 1024 + tid * 4;
    int row = f / 768;
    int k = f - row * 768;
    const float* sp;
    if (safe) sp = srcbase + f;
    else {
      int grow = base + row; if (grow > n - 1) grow = n - 1;
      sp = llm + (size_t)grow * 768 + k;
    }
    float4 v = *(const float4*)sp;
    f16x4 h;
    h[0] = (_Float16)v.x; h[1] = (_Float16)v.y;
    h[2] = (_Float16)v.z; h[3] = (_Float16)v.w;
    *(f16x4*)&As[row][k] = h;
  }
  __syncthreads();

  // ---- compute ----
  const int lane = tid & 63, wv = tid >> 6;
  const int g = lane >> 4, r16 = lane & 15;
  const int rowHalf = (wv & 1) * 16;
  const int cbase = (wv >> 1) * 2;   // this wave's two ct indices

  int arowG = base + rowHalf + r16; if (arowG > n - 1) arowG = n - 1;
  int nm = names[arowG], tp = types[arowG];

  f32x4 acc0, acc1;
  acc0[0] = 0.f; acc0[1] = 0.f; acc0[2] = 0.f; acc0[3] = 0.f;
  acc1 = acc0;

  #pragma unroll 4
  for (int c = 0; c < 24; ++c) {
    f16x8 b0 = *(const f16x8*)(Bf + ((size_t)(c * 4 + g) * 64 + cbase * 16 + r16) * 8);
    f16x8 b1 = *(const f16x8*)(Bf + ((size_t)(c * 4 + g) * 64 + (cbase + 1) * 16 + r16) * 8);
    f16x8 a = *(const f16x8*)&As[rowHalf + r16][c * 32 + g * 8];
    acc0 = __builtin_amdgcn_mfma_f32_16x16x32_f16(a, b0, acc0, 0, 0, 0);
    acc1 = __builtin_amdgcn_mfma_f32_16x16x32_f16(a, b1, acc1, 0, 0, 0);
  }

  // tail chunks 24..27: name(2), type|behav, behav|0
  auto tailStep = [&](int c, const float4& p, const float4& qv) {
    f16x8 b0 = *(const f16x8*)(Bf + ((size_t)(c * 4 + g) * 64 + cbase * 16 + r16) * 8);
    f16x8 b1 = *(const f16x8*)(Bf + ((size_t)(c * 4 + g) * 64 + (cbase + 1) * 16 + r16) * 8);
    f16x8 a = cvt8(p, qv);
    acc0 = __builtin_amdgcn_mfma_f32_16x16x32_f16(a, b0, acc0, 0, 0, 0);
    acc1 = __builtin_amdgcn_mfma_f32_16x16x32_f16(a, b1, acc1, 0, 0, 0);
  };

  {
    const float* pN = nemb + (size_t)nm * 64 + g * 8;
    tailStep(24, *(const float4*)pN, *(const float4*)(pN + 4));
    tailStep(25, *(const float4*)(pN + 32), *(const float4*)(pN + 36));
  }
  {
    const float* q0 = (g < 2) ? (temb + (size_t)tp * 16 + g * 8)
                              : (beh + (size_t)arowG * 32 + (size_t)(g - 2) * 8);
    tailStep(26, *(const float4*)q0, *(const float4*)(q0 + 4));
  }
  {
    const float4 z = make_float4(0.f, 0.f, 0.f, 0.f);
    const float* q1 = beh + (size_t)arowG * 32 + 16 + (size_t)(g & 1) * 8;
    float4 p = *(const float4*)q1, qv = *(const float4*)(q1 + 4);
    if (g >= 2) { p = z; qv = z; }
    tailStep(27, p, qv);
  }

  // epilogue: out(f16) = (acc + biasf) * dinv[node]
  int nodeBase = base + rowHalf + g * 4;
  float dv[4];
  #pragma unroll
  for (int rr = 0; rr < 4; ++rr) {
    int nd = nodeBase + rr;
    dv[rr] = dinv[nd < n ? nd : n - 1];
  }
  #pragma unroll
  for (int ct2 = 0; ct2 < 2; ++ct2) {
    int col = (cbase + ct2) * 16 + r16;
    float bfc = biasf[col];
    f32x4 av = (ct2 == 0) ? acc0 : acc1;
    #pragma unroll
    for (int rr = 0; rr < 4; ++rr) {
      int nd = nodeBase + rr;
      if (nd < n) out[(size_t)nd * 64 + col] = (_Float16)((av[rr] + bfc) * dv[rr]);
    }
  }
}

// ---------------- gemm2: pure f16, A-fragment = single 16B load, K=64 ----------------

__device__ __forceinline__ void loadBf(const _Float16* __restrict__ Bf, int c, int g, int r16,
                                       f16x8 (&bf)[4]) {
  #pragma unroll
  for (int ct = 0; ct < 4; ++ct)
    bf[ct] = *(const f16x8*)(Bf + ((size_t)(c * 4 + g) * 64 + ct * 16 + r16) * 8);
}

__device__ __forceinline__ void mfma8(f32x4 (&acc)[2][4], const f16x8& a0, const f16x8& a1,
                                      const f16x8 (&bf)[4]) {
  #pragma unroll
  for (int ct = 0; ct < 4; ++ct) {
    acc[0][ct] = __builtin_amdgcn_mfma_f32_16x16x32_f16(a0, bf[ct], acc[0][ct], 0, 0, 0);
    acc[1][ct] = __builtin_amdgcn_mfma_f32_16x16x32_f16(a1, bf[ct], acc[1][ct], 0, 0, 0);
  }
}

__global__ __launch_bounds__(256, 4) void gemm2_kernel(
    const _Float16* __restrict__ h, const _Float16* __restrict__ B2f,
    const float* __restrict__ dinv, _Float16* __restrict__ out, int n)
{
  int w = blockIdx.x * 4 + (threadIdx.x >> 6);
  int nw = (n + 31) >> 5;
  if (w >= nw) return;
  int lane = threadIdx.x & 63;
  int g = lane >> 4, r16 = lane & 15;
  int base = w * 32;
  int arow0 = base + r16;      if (arow0 > n - 1) arow0 = n - 1;
  int arow1 = base + 16 + r16; if (arow1 > n - 1) arow1 = n - 1;

  f32x4 acc[2][4];
  #pragma unroll
  for (int i = 0; i < 2; ++i)
    #pragma unroll
    for (int j = 0; j < 4; ++j) { acc[i][j][0] = 0.f; acc[i][j][1] = 0.f; acc[i][j][2] = 0.f; acc[i][j][3] = 0.f; }

  #pragma unroll
  for (int c = 0; c < 2; ++c) {
    f16x8 bf[4];
    loadBf(B2f, c, g, r16, bf);
    f16x8 a0 = *(const f16x8*)(h + (size_t)arow0 * 64 + c * 32 + g * 8);
    f16x8 a1 = *(const f16x8*)(h + (size_t)arow1 * 64 + c * 32 + g * 8);
    mfma8(acc, a0, a1, bf);
  }

  float dv0[4], dv1[4];
  #pragma unroll
  for (int rr = 0; rr < 4; ++rr) {
    int n0 = base + g * 4 + rr;      dv0[rr] = dinv[n0 < n ? n0 : n - 1];
    int n1 = base + 16 + g * 4 + rr; dv1[rr] = dinv[n1 < n ? n1 : n - 1];
  }
  #pragma unroll
  for (int ct = 0; ct < 4; ++ct) {
    int col = ct * 16 + r16;
    #pragma unroll
    for (int rr = 0; rr < 4; ++rr) {
      int node0 = base + g * 4 + rr;
      if (node0 < n) out[(size_t)node0 * 64 + col] = (_Float16)(acc[0][ct][rr] * dv0[rr]);
      int node1 = base + 16 + g * 4 + rr;
      if (node1 < n) out[(size_t)node1 * 64 + col] = (_Float16)(acc[1][ct][rr] * dv1[rr]);
    }
  }
}

// ---------------- aggregation (wave-per-node, shifted colp) ----------------
// out[j] = relu(bias + dj*(hp[j] + sum ew*hp[src])); hp dinv-prescaled f16.

__device__ __forceinline__ void storeOut(_Float16* p, float v) { *p = (_Float16)v; }
__device__ __forceinline__ void storeOut(float* p, float v) { *p = v; }

template <typename OUT>
__global__ __launch_bounds__(256) void agg_kernel(
    const _Float16* __restrict__ hp, const int* __restrict__ colp,
    const int2* __restrict__ csr, const float* __restrict__ dinv,
    const float* __restrict__ bias, OUT* __restrict__ out, int n)
{
  int wid = threadIdx.x >> 6, lane = threadIdx.x & 63;
  int j = blockIdx.x * 4 + wid;
  if (j >= n) return;
  float dj = dinv[j];
  float hj = (float)hp[(size_t)j * 64 + lane];
  int e0 = (j > 0) ? colp[j - 1] : 0;
  int e1 = colp[j];
  float s0 = 0.0f, s1 = 0.0f;
  int e = e0;
  for (; e + 8 <= e1; e += 8) {
    int2 m0 = csr[e],     m1 = csr[e + 1], m2 = csr[e + 2], m3 = csr[e + 3];
    int2 m4 = csr[e + 4], m5 = csr[e + 5], m6 = csr[e + 6], m7 = csr[e + 7];
    float f0 = (float)hp[(size_t)m0.x * 64 + lane];
    float f1 = (float)hp[(size_t)m1.x * 64 + lane];
    float f2 = (float)hp[(size_t)m2.x * 64 + lane];
    float f3 = (float)hp[(size_t)m3.x * 64 + lane];
    float f4 = (float)hp[(size_t)m4.x * 64 + lane];
    float f5 = (float)hp[(size_t)m5.x * 64 + lane];
    float f6 = (float)hp[(size_t)m6.x * 64 + lane];
    float f7 = (float)hp[(size_t)m7.x * 64 + lane];
    s0 = fmaf(__int_as_float(m0.y), f0, s0);
    s1 = fmaf(__int_as_float(m1.y), f1, s1);
    s0 = fmaf(__int_as_float(m2.y), f2, s0);
    s1 = fmaf(__int_as_float(m3.y), f3, s1);
    s0 = fmaf(__int_as_float(m4.y), f4, s0);
    s1 = fmaf(__int_as_float(m5.y), f5, s1);
    s0 = fmaf(__int_as_float(m6.y), f6, s0);
    s1 = fmaf(__int_as_float(m7.y), f7, s1);
  }
  for (; e + 2 <= e1; e += 2) {
    int2 m0 = csr[e], m1 = csr[e + 1];
    float f0 = (float)hp[(size_t)m0.x * 64 + lane];
    float f1 = (float)hp[(size_t)m1.x * 64 + lane];
    s0 = fmaf(__int_as_float(m0.y), f0, s0);
    s1 = fmaf(__int_as_float(m1.y), f1, s1);
  }
  if (e < e1) {
    int2 m = csr[e];
    s0 = fmaf(__int_as_float(m.y), (float)hp[(size_t)m.x * 64 + lane], s0);
  }
  float acc = bias[lane] + dj * (hj + s0 + s1);
  storeOut(out + (size_t)j * 64 + lane, fmaxf(acc, 0.0f));
}

// ---------------- pool + classifier ----------------

__global__ __launch_bounds__(256) void pool_kernel(const float* __restrict__ x,
                                                   const int* __restrict__ batch,
                                                   float* __restrict__ pooled, int n) {
  __shared__ float red[4][64];
  __shared__ int range_s[2];
  int gph = blockIdx.x;
  int tid = threadIdx.x, wid = tid >> 6, lane = tid & 63;
  if (tid < 2) {
    int target = gph + tid;
    int lo = 0, hi = n;
    while (lo < hi) { int m = (lo + hi) >> 1; if (batch[m] < target) lo = m + 1; else hi = m; }
    range_s[tid] = lo;
  }
  __syncthreads();
  int lo = range_s[0], hi = range_s[1];
  float acc = 0.0f;
  for (int i = lo + wid; i < hi; i += 4) acc += x[(size_t)i * 64 + lane];
  red[wid][lane] = acc;
  __syncthreads();
  if (tid < 64) {
    float sum = red[0][lane] + red[1][lane] + red[2][lane] + red[3][lane];
    float cntf = (float)(hi - lo);
    pooled[gph * 64 + lane] = sum / fmaxf(cntf, 1.0f);
  }
}

__global__ void cls_kernel(const float* __restrict__ pooled, const float* __restrict__ cw,
                           const float* __restrict__ cb, float* __restrict__ out) {
  int t = threadIdx.x;
  int gph = t >> 1, c = t & 1;
  float acc = cb[c];
  #pragma unroll 8
  for (int k = 0; k < 64; ++k) acc = fmaf(pooled[gph * 64 + k], cw[k * 2 + c], acc);
  out[gph * 2 + c] = acc;
}

// ---------------- launch ----------------

extern "C" void kernel_launch(void* const* d_in, const int* in_sizes, int n_in,
                              void* d_out, int out_size, void* d_ws, size_t ws_size,
                              hipStream_t stream) {
  const int*   x_names  = (const int*)  d_in[0];
  const int*   x_types  = (const int*)  d_in[1];
  const float* behav    = (const float*)d_in[2];
  const int*   ei       = (const int*)  d_in[3];
  const float* ew       = (const float*)d_in[4];
  const int*   batch    = (const int*)  d_in[5];
  const float* llm      = (const float*)d_in[6];
  const float* name_emb = (const float*)d_in[7];
  const float* type_emb = (const float*)d_in[8];
  const float* pw       = (const float*)d_in[9];
  const float* pb       = (const float*)d_in[10];
  const float* w1       = (const float*)d_in[11];
  const float* b1       = (const float*)d_in[12];
  const float* w2       = (const float*)d_in[13];
  const float* b2       = (const float*)d_in[14];
  const float* cw       = (const float*)d_in[15];
  const float* cb       = (const float*)d_in[16];

  const int N = in_sizes[0];
  const int E = in_sizes[4];
  const int nb = (N + 255) / 256;
  const int eb = (E + 255) / 256;
  const int g1blocks = (N + G1_ROWS - 1) / G1_ROWS;
  const int g2blocks = ((N + 31) / 32 + 3) / 4;

  char* p = (char*)d_ws;
  auto alloc = [&](size_t bytes) -> void* {
    void* r = (void*)p; p += (bytes + 255) & ~(size_t)255; return r;
  };
  float*     dinv   = (float*)    alloc((size_t)N * 4);
  int*       cnt    = (int*)      alloc((size_t)N * 4);
  int*       colp   = (int*)      alloc((size_t)(N + 1) * 4);
  int2*      csr    = (int2*)     alloc((size_t)E * 8);
  int*       bsum   = (int*)      alloc((size_t)(nb + 1) * 4);
  _Float16*  Bf     = (_Float16*) alloc((size_t)896 * 64 * 2);
  _Float16*  B2f    = (_Float16*) alloc((size_t)64 * 64 * 2);
  float*     biasf  = (float*)    alloc((size_t)64 * 4);
  _Float16*  hp1    = (_Float16*) alloc((size_t)N * 64 * 2);
  _Float16*  y1     = (_Float16*) alloc((size_t)N * 64 * 2);
  _Float16*  hp2    = (_Float16*) alloc((size_t)N * 64 * 2);
  float*     y2     = (float*)    alloc((size_t)N * 64 * 4);
  float*     pooled = (float*)    alloc((size_t)128 * 64 * 4);
  (void)ws_size; (void)n_in; (void)out_size;

  int prep_blocks = (896 * 64 + 64 + 64 * 64 + 255) / 256;
  if (prep_blocks < nb) prep_blocks = nb;   // also zeroes cnt
  prep_kernel<<<prep_blocks, 256, 0, stream>>>(pw, pb, w1, w2, Bf, biasf, B2f, cnt, N);
  cnt_kernel<<<eb, 256, 0, stream>>>(ei, cnt, E);
  scan_blk<<<nb, 256, 0, stream>>>(cnt, colp, bsum, N);
  scan_top<<<1, 512, 0, stream>>>(bsum, colp, nb, N);
  scan_add<<<nb, 256, 0, stream>>>(colp, bsum, N);
  fill_kernel<<<eb, 256, 0, stream>>>(ei, ew, colp, csr, E);
  degsum_kernel<<<nb, 256, 0, stream>>>(colp, csr, dinv, N);

  gemm1_kernel<<<g1blocks, 256, 0, stream>>>(llm, Bf, x_names, x_types, behav,
                                             name_emb, type_emb, biasf, dinv, hp1, N);
  agg_kernel<_Float16><<<(N + 3) / 4, 256, 0, stream>>>(hp1, colp, csr, dinv, b1, y1, N);
  gemm2_kernel<<<g2blocks, 256, 0, stream>>>(y1, B2f, dinv, hp2, N);
  agg_kernel<float><<<(N + 3) / 4, 256, 0, stream>>>(hp2, colp, csr, dinv, b2, y2, N);
  pool_kernel<<<128, 256, 0, stream>>>(y2, batch, pooled, N);
  cls_kernel<<<1, 256, 0, stream>>>(pooled, cw, cb, (float*)d_out);
}